// Round 12
// baseline (377.874 us; speedup 1.0000x reference)
//
#include <hip/hip_runtime.h>

#define NTOK 1024
#define CDIM 1024
#define CRDIM 256
#define ENUM 8
#define IDIM 4096
#define WSTRIDE 4194304ull  // C*I elements per expert weight matrix

typedef __bf16 bf16x8 __attribute__((ext_vector_type(8)));
typedef __bf16 bf16x4 __attribute__((ext_vector_type(4)));
typedef float f32x4 __attribute__((ext_vector_type(4)));

typedef const unsigned int __attribute__((address_space(1))) gu32;
typedef unsigned int __attribute__((address_space(3))) lu32;

__device__ __forceinline__ void glds16(const unsigned short* g, unsigned short* l) {
  __builtin_amdgcn_global_load_lds((gu32*)g, (lu32*)l, 16, 0, 0);
}

__device__ __forceinline__ unsigned short f2bf(float f) {
  union { float f; unsigned int u; } v; v.f = f;
  unsigned int r = v.u + 0x7FFFu + ((v.u >> 16) & 1u);  // RNE
  return (unsigned short)(r >> 16);
}

// ---- router block: RT tokens per block, x via cached global reads ----
#define RT 16
__device__ __forceinline__ void router_block(
    int rb, const float* __restrict__ x, const float* __restrict__ Wr1,
    const float* __restrict__ br1, const float* __restrict__ Wr2,
    const float* __restrict__ br2, int* __restrict__ ti, float* __restrict__ tw,
    char* pool) {
  float (*hs)[CRDIM] = (float(*)[CRDIM])pool;             // 16 KB
  float (*lg)[ENUM] = (float(*)[ENUM])(pool + 16384);     // 512 B
  const int tid = threadIdx.x;
  const int tok0 = rb * RT;
  float acc[RT];
#pragma unroll
  for (int r = 0; r < RT; ++r) acc[r] = 0.f;
  const int j = tid;
  const float* xrow = x + (size_t)tok0 * CDIM;
  for (int i = 0; i < CDIM; ++i) {
    float w = Wr1[(size_t)i * CRDIM + j];
#pragma unroll
    for (int r = 0; r < RT; ++r) acc[r] += xrow[r * CDIM + i] * w;
  }
  float b = br1[j];
#pragma unroll
  for (int r = 0; r < RT; ++r) hs[r][j] = fmaxf(acc[r] + b, 0.f);
  __syncthreads();
  if (tid < RT * ENUM) {
    int r = tid >> 3, e = tid & 7;
    float a = 0.f;
    for (int i = 0; i < CRDIM; ++i) a += hs[r][i] * Wr2[(size_t)i * ENUM + e];
    lg[r][e] = a + br2[e];
  }
  __syncthreads();
  if (tid < RT) {
    int r = tid;
    float m = lg[r][0];
#pragma unroll
    for (int e = 1; e < 8; ++e) m = fmaxf(m, lg[r][e]);
    float s = 0.f, g[8];
#pragma unroll
    for (int e = 0; e < 8; ++e) { g[e] = expf(lg[r][e] - m); s += g[e]; }
    float inv = 1.f / s;
    int i0 = 0; float g0 = -1.f;
#pragma unroll
    for (int e = 0; e < 8; ++e) { float ge = g[e] * inv; if (ge > g0) { g0 = ge; i0 = e; } }
    int i1 = 0; float g1 = -2.f;
#pragma unroll
    for (int e = 0; e < 8; ++e) { float ge = g[e] * inv; if (e != i0 && ge > g1) { g1 = ge; i1 = e; } }
    float w0 = 1.f / (1.f + expf((g1 - g0) * 0.5f));
    int n = tok0 + r;
    ti[2 * n] = i0; ti[2 * n + 1] = i1;
    tw[2 * n] = w0; tw[2 * n + 1] = 1.f - w0;
  }
}

// prep: [0,1024) cast x->bf16; [1024,1088) router (16 tokens/block)
__global__ __launch_bounds__(256) void prep_kernel(
    const float* __restrict__ x, unsigned short* __restrict__ xb,
    const float* __restrict__ Wr1, const float* __restrict__ br1,
    const float* __restrict__ Wr2, const float* __restrict__ br2,
    int* __restrict__ ti, float* __restrict__ tw) {
  __shared__ __align__(16) char pool[16896];
  const int b = blockIdx.x;
  if (b < 1024) {
    int t = b * 256 + threadIdx.x;
    float4 v = reinterpret_cast<const float4*>(x)[t];
    ushort4 o;
    o.x = f2bf(v.x); o.y = f2bf(v.y); o.z = f2bf(v.z); o.w = f2bf(v.w);
    reinterpret_cast<ushort4*>(xb)[t] = o;
  } else {
    router_block(b - 1024, x, Wr1, br1, Wr2, br2, ti, tw, pool);
  }
}

// ---------------- per-expert token lists (stable order) + tokslot map ---------
__global__ __launch_bounds__(1024) void build_lists_kernel(
    const int* __restrict__ ti, const float* __restrict__ tw,
    int* __restrict__ cnt, int* __restrict__ list, int* __restrict__ tokslot) {
  __shared__ int s[NTOK];
  const int e = blockIdx.x, n = threadIdx.x;
  int a = ti[2 * n], b = ti[2 * n + 1];
  int flag = (a == e || b == e) ? 1 : 0;
  s[n] = flag;
  __syncthreads();
  for (int off = 1; off < NTOK; off <<= 1) {
    int v = (n >= off) ? s[n - off] : 0;
    __syncthreads();
    s[n] += v;
    __syncthreads();
  }
  if (flag) {
    int pos = s[n] - 1;
    list[e * NTOK + pos] = n;
    int slot = (a == e) ? 0 : 1;
    tokslot[2 * n + slot] = (e << 16) | pos;
  }
  if (n == NTOK - 1) cnt[e] = s[n];
}

// uniform helper: y -> (expert, row0, hbase) over 256-row tiles
__device__ __forceinline__ bool tile_lookup(const int* __restrict__ cnt, int y,
                                            int& e_out, int& row0_out,
                                            int& hbase_out) {
  int c[8];
#pragma unroll
  for (int i = 0; i < 8; ++i) c[i] = cnt[i];
  int k = 0, found = -1, r0 = 0, pre = 0, hb = 0;
#pragma unroll
  for (int ee = 0; ee < 9; ++ee) {
    int me = (ee < 8) ? c[ee] : NTOK;
    int nt_e = (me + 255) >> 8;
    if (found < 0 && y < k + nt_e) {
      found = ee; r0 = (y - k) << 8; hb = (ee < 8) ? pre : 2048;
    }
    k += nt_e;
    if (ee < 8) pre += me;
  }
  if (found < 0) return false;
  e_out = found; row0_out = r0; hbase_out = hb;
  return true;
}

// ---- 512-thread 256x128 GEMM, direct f32 weights, counted-vmcnt pipeline ----
// (round-9 structure: A 3-deep glds16; B 2-LDS-buf + 2-reg-set bridge; vmcnt(4))
// MODE 0: H[hrow] = silu(Xg @ W1 + b1)            (bf16 store)
// MODE 1: pout[kc][hrow] = H @ W2 (+b2 @ kc==0)   (f32 plain store, split-K=4)
template <int MODE>
__global__ __launch_bounds__(512, 4) void gemm_w(
    const unsigned short* __restrict__ Abase,
    const float* __restrict__ Wr, const float* __restrict__ Wsh,
    const float* __restrict__ br, const float* __restrict__ bsh,
    const int* __restrict__ cnt, const int* __restrict__ list,
    unsigned short* __restrict__ Hout, float* __restrict__ pout) {
  __shared__ __align__(16) unsigned short smA[3 * 8192];  // 3 x [256m][32k] bf16
  __shared__ __align__(16) unsigned short smB[2 * 5120];  // 2 x [128n][40] bf16
  int e, row0, hbase;
  if (!tile_lookup(cnt, blockIdx.y, e, row0, hbase)) return;
  const int nt = (MODE == 0) ? blockIdx.x : (blockIdx.x & 7);
  const int kc = (MODE == 0) ? 0 : (blockIdx.x >> 3);

  constexpr int KD = (MODE == 0) ? CDIM : IDIM;  // A row length
  constexpr int ND = (MODE == 0) ? IDIM : CDIM;  // B row length (f32 [K][N])
  constexpr int NT = 32;                         // K-chunk 1024 / BK 32
  const int me = (e < 8) ? cnt[e] : NTOK;
  const int valid = min(256, me - row0);
  const int n0 = nt * 128;
  const float* Bsrc = (e < 8) ? (Wr + (size_t)e * WSTRIDE) : Wsh;
  const float* bias = (e < 8) ? (br + (size_t)e * ND) : bsh;
  const int tid = threadIdx.x;
  const int lane = tid & 63, w = tid >> 6;
  const int kbeg = kc * 1024;

  // ---- A staging (glds16): wave w rows [32w,32w+16) and [32w+16,32w+32) ----
  const int rl = lane >> 2, cs = lane & 3;
  const int r0w = 32 * w + rl;
  const int q0 = cs ^ ((r0w >> 1) & 3);
  const int q1 = cs ^ (((r0w + 16) >> 1) & 3);
  int src_r0, src_r1;
  if (MODE == 0) {
    if (e < 8) {
      src_r0 = list[e * NTOK + row0 + min(r0w, valid - 1)];
      src_r1 = list[e * NTOK + row0 + min(r0w + 16, valid - 1)];
    } else {
      src_r0 = row0 + min(r0w, valid - 1);
      src_r1 = row0 + min(r0w + 16, valid - 1);
    }
  } else {
    src_r0 = hbase + row0 + min(r0w, valid - 1);
    src_r1 = hbase + row0 + min(r0w + 16, valid - 1);
  }
  const unsigned short* srcA0 = Abase + (size_t)src_r0 * KD + kbeg + q0 * 8;
  const unsigned short* srcA1 = Abase + (size_t)src_r1 * KD + kbeg + q1 * 8;
  const int aB0 = (32 * w) * 32;
  const int aB1 = (32 * w + 16) * 32;

  // ---- B staging: thread -> 4 cols {c4..c4+3} at k-pair kp ----
  const int c4 = (tid & 31) * 4;
  const int kp = tid >> 5;  // 0..15
  const float* srcB = Bsrc + (size_t)(kbeg + 2 * kp) * ND + n0 + c4;

  // ---- fragment offsets: wave grid 4M x 2N; per-wave 64m x 64n ----
  const int wr = (w >> 1) * 64, wc = (w & 1) * 64;
  const int lr = lane & 15, q = lane >> 4;
  int offA[4], offB0[4];
#pragma unroll
  for (int m = 0; m < 4; ++m) {
    int R = wr + m * 16 + lr;
    offA[m] = R * 32 + (q ^ ((R >> 1) & 3)) * 8;
  }
#pragma unroll
  for (int n = 0; n < 4; ++n) {
    int R = wc + n * 16 + lr;
    int u = (R >> 3) & 7;
    offB0[n] = R * 40 + ((2 * q) ^ u) * 4;  // hi half at ^4
  }

  f32x4 acc[4][4];
#pragma unroll
  for (int m = 0; m < 4; ++m)
#pragma unroll
    for (int n = 0; n < 4; ++n) acc[m][n] = (f32x4)0.f;

  unsigned short *ca = smA, *na = smA + 8192, *wa = smA + 16384;
  unsigned short *bc = smB, *bn = smB + 5120;
  f32x4 rbA[2], rbB[2];

#define ASTG(T, BA)                                       \
  {                                                       \
    glds16(srcA0 + (size_t)(T) * 32, (BA) + aB0);         \
    glds16(srcA1 + (size_t)(T) * 32, (BA) + aB1);         \
  }
#define BLOAD(T, R)                                       \
  {                                                       \
    const float* bp = srcB + (size_t)(T) * 32 * ND;       \
    R[0] = *reinterpret_cast<const f32x4*>(bp);           \
    R[1] = *reinterpret_cast<const f32x4*>(bp + ND);      \
  }
#define BWRITE(R, BB)                                                          \
  {                                                                            \
    _Pragma("unroll") for (int j = 0; j < 4; ++j) {                            \
      int col = c4 + j;                                                        \
      int kp2 = kp ^ (2 * ((col >> 3) & 7));                                   \
      unsigned int pk =                                                        \
          (unsigned int)__builtin_bit_cast(unsigned short, (__bf16)R[0][j]) |  \
          ((unsigned int)__builtin_bit_cast(unsigned short, (__bf16)R[1][j])   \
           << 16);                                                             \
      *reinterpret_cast<unsigned int*>((BB) + col * 40 + kp2 * 2) = pk;        \
    }                                                                          \
  }
#define MFMAS()                                                                \
  {                                                                            \
    bf16x8 av[4];                                                              \
    _Pragma("unroll") for (int m = 0; m < 4; ++m)                              \
        av[m] = *reinterpret_cast<const bf16x8*>(ca + offA[m]);                \
    _Pragma("unroll") for (int n = 0; n < 4; ++n) {                            \
      bf16x4 lo = *reinterpret_cast<const bf16x4*>(bc + offB0[n]);             \
      bf16x4 hi = *reinterpret_cast<const bf16x4*>(bc + (offB0[n] ^ 4));       \
      bf16x8 bv = __builtin_shufflevector(lo, hi, 0, 1, 2, 3, 4, 5, 6, 7);     \
      _Pragma("unroll") for (int m = 0; m < 4; ++m)                            \
          acc[m][n] = __builtin_amdgcn_mfma_f32_16x16x32_bf16(av[m], bv,       \
                                                              acc[m][n], 0,   \
                                                              0, 0);           \
    }                                                                          \
  }

  // prologue: tiles 0,1 in flight; publish tile 0
  ASTG(0, ca); BLOAD(0, rbA);
  __builtin_amdgcn_sched_barrier(0);
  ASTG(1, na); BLOAD(1, rbB);
  asm volatile("s_waitcnt vmcnt(4)" ::: "memory");  // tile0 A in LDS, B in regs
  __builtin_amdgcn_sched_barrier(0);
  BWRITE(rbA, bc);
  asm volatile("s_waitcnt lgkmcnt(0)" ::: "memory");
  __builtin_amdgcn_s_barrier();
  __builtin_amdgcn_sched_barrier(0);

#define GBODY(T, RL, RW)                                                     \
  {                                                                          \
    if ((T) + 2 < NT) { ASTG((T) + 2, wa); BLOAD((T) + 2, RL); }             \
    MFMAS();                                                                 \
    if ((T) + 1 < NT) {                                                      \
      if ((T) + 2 < NT) {                                                    \
        asm volatile("s_waitcnt vmcnt(4)" ::: "memory");                     \
      } else {                                                               \
        asm volatile("s_waitcnt vmcnt(0)" ::: "memory");                     \
      }                                                                      \
      __builtin_amdgcn_sched_barrier(0);                                     \
      BWRITE(RW, bn);                                                        \
      asm volatile("s_waitcnt lgkmcnt(0)" ::: "memory");                     \
      __builtin_amdgcn_s_barrier();                                          \
      __builtin_amdgcn_sched_barrier(0);                                     \
    }                                                                        \
    { unsigned short* tp = ca; ca = na; na = wa; wa = tp; }                  \
    { unsigned short* tp = bc; bc = bn; bn = tp; }                           \
  }

  for (int t = 0; t < NT; t += 2) {
    GBODY(t, rbA, rbB)
    GBODY(t + 1, rbB, rbA)
  }
#undef GBODY
#undef MFMAS
#undef BWRITE
#undef BLOAD
#undef ASTG

  const int rbase = wr + (q << 2);
#pragma unroll
  for (int n = 0; n < 4; ++n) {
    const int col = n0 + wc + n * 16 + lr;
    const float bval = (MODE == 0 || kc == 0) ? bias[col] : 0.f;
#pragma unroll
    for (int m = 0; m < 4; ++m) {
#pragma unroll
      for (int r = 0; r < 4; ++r) {
        const int i = rbase + m * 16 + r;
        if (i < valid) {
          float v = acc[m][n][r] + bval;
          if (MODE == 0) {
            float sv = v / (1.f + __expf(-v));
            Hout[(size_t)(hbase + row0 + i) * IDIM + col] = f2bf(sv);
          } else {
            pout[((size_t)kc * 3072 + hbase + row0 + i) * CDIM + col] = v;
          }
        }
      }
    }
  }
}

// out[tok][c] = sum_kc( pout[kc][shared] + g0*pout[kc][h0] + g1*pout[kc][h1] )
__global__ __launch_bounds__(256) void reduce_kernel(
    const float* __restrict__ pout, const int* __restrict__ tokslot,
    const float* __restrict__ tw, const int* __restrict__ cnt,
    float* __restrict__ out) {
  const int tok = blockIdx.x;
  const int c = threadIdx.x * 4;
  int offs[8];
  {
    int o = 0;
#pragma unroll
    for (int e = 0; e < 8; ++e) { offs[e] = o; o += cnt[e]; }
  }
  const int t0 = tokslot[2 * tok], t1 = tokslot[2 * tok + 1];
  const float g0 = tw[2 * tok], g1 = tw[2 * tok + 1];
  const int r0 = offs[t0 >> 16] + (t0 & 0xffff);
  const int r1 = offs[t1 >> 16] + (t1 & 0xffff);
  const int rs = 2048 + tok;
  float4 acc; acc.x = 0.f; acc.y = 0.f; acc.z = 0.f; acc.w = 0.f;
#pragma unroll
  for (int kc = 0; kc < 4; ++kc) {
    const float* base = pout + (size_t)kc * 3072 * CDIM;
    float4 a = *reinterpret_cast<const float4*>(base + (size_t)rs * CDIM + c);
    float4 b = *reinterpret_cast<const float4*>(base + (size_t)r0 * CDIM + c);
    float4 d = *reinterpret_cast<const float4*>(base + (size_t)r1 * CDIM + c);
    acc.x += a.x + g0 * b.x + g1 * d.x;
    acc.y += a.y + g0 * b.y + g1 * d.y;
    acc.z += a.z + g0 * b.z + g1 * d.z;
    acc.w += a.w + g0 * b.w + g1 * d.w;
  }
  *reinterpret_cast<float4*>(out + (size_t)tok * CDIM + c) = acc;
}

extern "C" void kernel_launch(void* const* d_in, const int* in_sizes, int n_in,
                              void* d_out, int out_size, void* d_ws, size_t ws_size,
                              hipStream_t stream) {
  const float* x = (const float*)d_in[0];
  const float* Wr1 = (const float*)d_in[1];
  const float* br1 = (const float*)d_in[2];
  const float* Wr2 = (const float*)d_in[3];
  const float* br2 = (const float*)d_in[4];
  const float* Ws1 = (const float*)d_in[5];
  const float* bs1 = (const float*)d_in[6];
  const float* Ws2 = (const float*)d_in[7];
  const float* bs2 = (const float*)d_in[8];
  const float* We1 = (const float*)d_in[9];
  const float* be1 = (const float*)d_in[10];
  const float* We2 = (const float*)d_in[11];
  const float* be2 = (const float*)d_in[12];
  float* out = (float*)d_out;

  char* ws = (char*)d_ws;
  unsigned short* xb = (unsigned short*)(ws + 0);            // 2 MB
  int* ti = (int*)(ws + 2097152);
  float* tw = (float*)(ws + 2105344);
  int* cnt = (int*)(ws + 2113536);
  int* list = (int*)(ws + 2114048);                          // 32 KB
  unsigned short* H = (unsigned short*)(ws + 2179584);       // 24 MB -> 27345408
  int* tokslot = (int*)(ws + 27345920);                      // 8 KB -> 27354112
  float* pout = (float*)(ws + 27354112ull);                  // 48 MB -> 77687808

  prep_kernel<<<1088, 256, 0, stream>>>(x, xb, Wr1, br1, Wr2, br2, ti, tw);
  build_lists_kernel<<<8, 1024, 0, stream>>>(ti, tw, cnt, list, tokslot);
  gemm_w<0><<<dim3(32, 20), 512, 0, stream>>>(xb, We1, Ws1, be1, bs1, cnt, list,
                                              H, nullptr);
  gemm_w<1><<<dim3(32, 20), 512, 0, stream>>>(H, We2, Ws2, be2, bs2, cnt, list,
                                              nullptr, pout);
  reduce_kernel<<<1024, 256, 0, stream>>>(pout, tokslot, tw, cnt, out);
}

// Round 13
// 237.034 us; speedup vs baseline: 1.5942x; 1.5942x over previous
//
#include <hip/hip_runtime.h>

#define NTOK 1024
#define CDIM 1024
#define CRDIM 256
#define ENUM 8
#define IDIM 4096
#define WSTRIDE 4194304ull  // C*I elements per expert weight matrix

typedef __bf16 bf16x8 __attribute__((ext_vector_type(8)));
typedef __bf16 bf16x4 __attribute__((ext_vector_type(4)));
typedef float f32x4 __attribute__((ext_vector_type(4)));

typedef const unsigned int __attribute__((address_space(1))) gu32;
typedef unsigned int __attribute__((address_space(3))) lu32;

__device__ __forceinline__ void glds16(const unsigned short* g, unsigned short* l) {
  __builtin_amdgcn_global_load_lds((gu32*)g, (lu32*)l, 16, 0, 0);
}

__device__ __forceinline__ unsigned short f2bf(float f) {
  union { float f; unsigned int u; } v; v.f = f;
  unsigned int r = v.u + 0x7FFFu + ((v.u >> 16) & 1u);  // RNE
  return (unsigned short)(r >> 16);
}

// ---------------- cast x to bf16 ----------------
__global__ __launch_bounds__(256) void init_cast_kernel(
    const float* __restrict__ x, unsigned short* __restrict__ xb) {
  int t = blockIdx.x * 256 + threadIdx.x;
  float4 v = reinterpret_cast<const float4*>(x)[t];
  ushort4 o;
  o.x = f2bf(v.x); o.y = f2bf(v.y); o.z = f2bf(v.z); o.w = f2bf(v.w);
  reinterpret_cast<ushort4*>(xb)[t] = o;
}

// ---------------- router: gates + top-2 (LDS x-stage, round-0..8 form) --------
#define RT 8
__global__ __launch_bounds__(256) void router_kernel(
    const float* __restrict__ x, const float* __restrict__ Wr1,
    const float* __restrict__ br1, const float* __restrict__ Wr2,
    const float* __restrict__ br2, int* __restrict__ ti,
    float* __restrict__ tw) {
  __shared__ float xs[RT][CDIM];
  __shared__ float hs[RT][CRDIM];
  __shared__ float lg[RT][ENUM];
  const int tid = threadIdx.x;
  const int tok0 = blockIdx.x * RT;
  for (int r = 0; r < RT; ++r) {
    float4 v = reinterpret_cast<const float4*>(x + (size_t)(tok0 + r) * CDIM)[tid];
    *reinterpret_cast<float4*>(&xs[r][tid * 4]) = v;
  }
  __syncthreads();
  float acc[RT];
#pragma unroll
  for (int r = 0; r < RT; ++r) acc[r] = 0.f;
  const int j = tid;
  for (int i = 0; i < CDIM; ++i) {
    float w = Wr1[(size_t)i * CRDIM + j];
#pragma unroll
    for (int r = 0; r < RT; ++r) acc[r] += xs[r][i] * w;
  }
  float b = br1[j];
#pragma unroll
  for (int r = 0; r < RT; ++r) hs[r][j] = fmaxf(acc[r] + b, 0.f);
  __syncthreads();
  if (tid < RT * ENUM) {
    int r = tid >> 3, e = tid & 7;
    float a = 0.f;
    for (int i = 0; i < CRDIM; ++i) a += hs[r][i] * Wr2[(size_t)i * ENUM + e];
    lg[r][e] = a + br2[e];
  }
  __syncthreads();
  if (tid < RT) {
    int r = tid;
    float m = lg[r][0];
#pragma unroll
    for (int e = 1; e < 8; ++e) m = fmaxf(m, lg[r][e]);
    float s = 0.f, g[8];
#pragma unroll
    for (int e = 0; e < 8; ++e) { g[e] = expf(lg[r][e] - m); s += g[e]; }
    float inv = 1.f / s;
    int i0 = 0; float g0 = -1.f;
#pragma unroll
    for (int e = 0; e < 8; ++e) { float ge = g[e] * inv; if (ge > g0) { g0 = ge; i0 = e; } }
    int i1 = 0; float g1 = -2.f;
#pragma unroll
    for (int e = 0; e < 8; ++e) { float ge = g[e] * inv; if (e != i0 && ge > g1) { g1 = ge; i1 = e; } }
    float w0 = 1.f / (1.f + expf((g1 - g0) * 0.5f));
    int n = tok0 + r;
    ti[2 * n] = i0; ti[2 * n + 1] = i1;
    tw[2 * n] = w0; tw[2 * n + 1] = 1.f - w0;
  }
}

// ---------------- per-expert token lists (stable order) + tokslot map ---------
__global__ __launch_bounds__(1024) void build_lists_kernel(
    const int* __restrict__ ti, const float* __restrict__ tw,
    int* __restrict__ cnt, int* __restrict__ list, int* __restrict__ tokslot) {
  __shared__ int s[NTOK];
  const int e = blockIdx.x, n = threadIdx.x;
  int a = ti[2 * n], b = ti[2 * n + 1];
  int flag = (a == e || b == e) ? 1 : 0;
  s[n] = flag;
  __syncthreads();
  for (int off = 1; off < NTOK; off <<= 1) {
    int v = (n >= off) ? s[n - off] : 0;
    __syncthreads();
    s[n] += v;
    __syncthreads();
  }
  if (flag) {
    int pos = s[n] - 1;
    list[e * NTOK + pos] = n;
    int slot = (a == e) ? 0 : 1;
    tokslot[2 * n + slot] = (e << 16) | pos;
  }
  if (n == NTOK - 1) cnt[e] = s[n];
}

// uniform helper: y -> (expert, row0, hbase) over 256-row tiles
__device__ __forceinline__ bool tile_lookup(const int* __restrict__ cnt, int y,
                                            int& e_out, int& row0_out,
                                            int& hbase_out) {
  int c[8];
#pragma unroll
  for (int i = 0; i < 8; ++i) c[i] = cnt[i];
  int k = 0, found = -1, r0 = 0, pre = 0, hb = 0;
#pragma unroll
  for (int ee = 0; ee < 9; ++ee) {
    int me = (ee < 8) ? c[ee] : NTOK;
    int nt_e = (me + 255) >> 8;
    if (found < 0 && y < k + nt_e) {
      found = ee; r0 = (y - k) << 8; hb = (ee < 8) ? pre : 2048;
    }
    k += nt_e;
    if (ee < 8) pre += me;
  }
  if (found < 0) return false;
  e_out = found; row0_out = r0; hbase_out = hb;
  return true;
}

// ---- 512-thread 256x128 GEMM, direct f32 weights, counted-vmcnt pipeline ----
// (round-9 structure: A 3-deep glds16; B 2-LDS-buf + 2-reg-set bridge; vmcnt(4))
// MODE 0: H[hrow] = silu(Xg @ W1 + b1)            (bf16 store)
// MODE 1: pout[kc][hrow] = H @ W2 (+b2 @ kc==0)   (f32 plain store, split-K=4)
template <int MODE>
__global__ __launch_bounds__(512, 4) void gemm_w(
    const unsigned short* __restrict__ Abase,
    const float* __restrict__ Wr, const float* __restrict__ Wsh,
    const float* __restrict__ br, const float* __restrict__ bsh,
    const int* __restrict__ cnt, const int* __restrict__ list,
    unsigned short* __restrict__ Hout, float* __restrict__ pout) {
  __shared__ __align__(16) unsigned short smA[3 * 8192];  // 3 x [256m][32k] bf16
  __shared__ __align__(16) unsigned short smB[2 * 5120];  // 2 x [128n][40] bf16
  int e, row0, hbase;
  if (!tile_lookup(cnt, blockIdx.y, e, row0, hbase)) return;
  const int nt = (MODE == 0) ? blockIdx.x : (blockIdx.x & 7);
  const int kc = (MODE == 0) ? 0 : (blockIdx.x >> 3);

  constexpr int KD = (MODE == 0) ? CDIM : IDIM;  // A row length
  constexpr int ND = (MODE == 0) ? IDIM : CDIM;  // B row length (f32 [K][N])
  constexpr int NT = 32;                         // K-chunk 1024 / BK 32
  const int me = (e < 8) ? cnt[e] : NTOK;
  const int valid = min(256, me - row0);
  const int n0 = nt * 128;
  const float* Bsrc = (e < 8) ? (Wr + (size_t)e * WSTRIDE) : Wsh;
  const float* bias = (e < 8) ? (br + (size_t)e * ND) : bsh;
  const int tid = threadIdx.x;
  const int lane = tid & 63, w = tid >> 6;
  const int kbeg = kc * 1024;

  // ---- A staging (glds16): wave w rows [32w,32w+16) and [32w+16,32w+32) ----
  const int rl = lane >> 2, cs = lane & 3;
  const int r0w = 32 * w + rl;
  const int q0 = cs ^ ((r0w >> 1) & 3);
  const int q1 = cs ^ (((r0w + 16) >> 1) & 3);
  int src_r0, src_r1;
  if (MODE == 0) {
    if (e < 8) {
      src_r0 = list[e * NTOK + row0 + min(r0w, valid - 1)];
      src_r1 = list[e * NTOK + row0 + min(r0w + 16, valid - 1)];
    } else {
      src_r0 = row0 + min(r0w, valid - 1);
      src_r1 = row0 + min(r0w + 16, valid - 1);
    }
  } else {
    src_r0 = hbase + row0 + min(r0w, valid - 1);
    src_r1 = hbase + row0 + min(r0w + 16, valid - 1);
  }
  const unsigned short* srcA0 = Abase + (size_t)src_r0 * KD + kbeg + q0 * 8;
  const unsigned short* srcA1 = Abase + (size_t)src_r1 * KD + kbeg + q1 * 8;
  const int aB0 = (32 * w) * 32;
  const int aB1 = (32 * w + 16) * 32;

  // ---- B staging: thread -> 4 cols {c4..c4+3} at k-pair kp ----
  const int c4 = (tid & 31) * 4;
  const int kp = tid >> 5;  // 0..15
  const float* srcB = Bsrc + (size_t)(kbeg + 2 * kp) * ND + n0 + c4;

  // ---- fragment offsets: wave grid 4M x 2N; per-wave 64m x 64n ----
  const int wr = (w >> 1) * 64, wc = (w & 1) * 64;
  const int lr = lane & 15, q = lane >> 4;
  int offA[4], offB0[4];
#pragma unroll
  for (int m = 0; m < 4; ++m) {
    int R = wr + m * 16 + lr;
    offA[m] = R * 32 + (q ^ ((R >> 1) & 3)) * 8;
  }
#pragma unroll
  for (int n = 0; n < 4; ++n) {
    int R = wc + n * 16 + lr;
    int u = (R >> 3) & 7;
    offB0[n] = R * 40 + ((2 * q) ^ u) * 4;  // hi half at ^4
  }

  f32x4 acc[4][4];
#pragma unroll
  for (int m = 0; m < 4; ++m)
#pragma unroll
    for (int n = 0; n < 4; ++n) acc[m][n] = (f32x4)0.f;

  unsigned short *ca = smA, *na = smA + 8192, *wa = smA + 16384;
  unsigned short *bc = smB, *bn = smB + 5120;
  f32x4 rbA[2], rbB[2];

#define ASTG(T, BA)                                       \
  {                                                       \
    glds16(srcA0 + (size_t)(T) * 32, (BA) + aB0);         \
    glds16(srcA1 + (size_t)(T) * 32, (BA) + aB1);         \
  }
#define BLOAD(T, R)                                       \
  {                                                       \
    const float* bp = srcB + (size_t)(T) * 32 * ND;       \
    R[0] = *reinterpret_cast<const f32x4*>(bp);           \
    R[1] = *reinterpret_cast<const f32x4*>(bp + ND);      \
  }
#define BWRITE(R, BB)                                                          \
  {                                                                            \
    _Pragma("unroll") for (int j = 0; j < 4; ++j) {                            \
      int col = c4 + j;                                                        \
      int kp2 = kp ^ (2 * ((col >> 3) & 7));                                   \
      unsigned int pk =                                                        \
          (unsigned int)__builtin_bit_cast(unsigned short, (__bf16)R[0][j]) |  \
          ((unsigned int)__builtin_bit_cast(unsigned short, (__bf16)R[1][j])   \
           << 16);                                                             \
      *reinterpret_cast<unsigned int*>((BB) + col * 40 + kp2 * 2) = pk;        \
    }                                                                          \
  }
#define MFMAS()                                                                \
  {                                                                            \
    bf16x8 av[4];                                                              \
    _Pragma("unroll") for (int m = 0; m < 4; ++m)                              \
        av[m] = *reinterpret_cast<const bf16x8*>(ca + offA[m]);                \
    _Pragma("unroll") for (int n = 0; n < 4; ++n) {                            \
      bf16x4 lo = *reinterpret_cast<const bf16x4*>(bc + offB0[n]);             \
      bf16x4 hi = *reinterpret_cast<const bf16x4*>(bc + (offB0[n] ^ 4));       \
      bf16x8 bv = __builtin_shufflevector(lo, hi, 0, 1, 2, 3, 4, 5, 6, 7);     \
      _Pragma("unroll") for (int m = 0; m < 4; ++m)                            \
          acc[m][n] = __builtin_amdgcn_mfma_f32_16x16x32_bf16(av[m], bv,       \
                                                              acc[m][n], 0,   \
                                                              0, 0);           \
    }                                                                          \
  }

  // prologue: tiles 0,1 in flight; publish tile 0
  ASTG(0, ca); BLOAD(0, rbA);
  __builtin_amdgcn_sched_barrier(0);
  ASTG(1, na); BLOAD(1, rbB);
  asm volatile("s_waitcnt vmcnt(4)" ::: "memory");  // tile0 A in LDS, B in regs
  __builtin_amdgcn_sched_barrier(0);
  BWRITE(rbA, bc);
  asm volatile("s_waitcnt lgkmcnt(0)" ::: "memory");
  __builtin_amdgcn_s_barrier();
  __builtin_amdgcn_sched_barrier(0);

#define GBODY(T, RL, RW)                                                     \
  {                                                                          \
    if ((T) + 2 < NT) { ASTG((T) + 2, wa); BLOAD((T) + 2, RL); }             \
    MFMAS();                                                                 \
    if ((T) + 1 < NT) {                                                      \
      if ((T) + 2 < NT) {                                                    \
        asm volatile("s_waitcnt vmcnt(4)" ::: "memory");                     \
      } else {                                                               \
        asm volatile("s_waitcnt vmcnt(0)" ::: "memory");                     \
      }                                                                      \
      __builtin_amdgcn_sched_barrier(0);                                     \
      BWRITE(RW, bn);                                                        \
      asm volatile("s_waitcnt lgkmcnt(0)" ::: "memory");                     \
      __builtin_amdgcn_s_barrier();                                          \
      __builtin_amdgcn_sched_barrier(0);                                     \
    }                                                                        \
    { unsigned short* tp = ca; ca = na; na = wa; wa = tp; }                  \
    { unsigned short* tp = bc; bc = bn; bn = tp; }                           \
  }

  for (int t = 0; t < NT; t += 2) {
    GBODY(t, rbA, rbB)
    GBODY(t + 1, rbB, rbA)
  }
#undef GBODY
#undef MFMAS
#undef BWRITE
#undef BLOAD
#undef ASTG

  const int rbase = wr + (q << 2);
#pragma unroll
  for (int n = 0; n < 4; ++n) {
    const int col = n0 + wc + n * 16 + lr;
    const float bval = (MODE == 0 || kc == 0) ? bias[col] : 0.f;
#pragma unroll
    for (int m = 0; m < 4; ++m) {
#pragma unroll
      for (int r = 0; r < 4; ++r) {
        const int i = rbase + m * 16 + r;
        if (i < valid) {
          float v = acc[m][n][r] + bval;
          if (MODE == 0) {
            float sv = v / (1.f + __expf(-v));
            Hout[(size_t)(hbase + row0 + i) * IDIM + col] = f2bf(sv);
          } else {
            pout[((size_t)kc * 3072 + hbase + row0 + i) * CDIM + col] = v;
          }
        }
      }
    }
  }
}

// out[tok][c] = sum_kc( pout[kc][shared] + g0*pout[kc][h0] + g1*pout[kc][h1] )
__global__ __launch_bounds__(256) void reduce_kernel(
    const float* __restrict__ pout, const int* __restrict__ tokslot,
    const float* __restrict__ tw, const int* __restrict__ cnt,
    float* __restrict__ out) {
  const int tok = blockIdx.x;
  const int c = threadIdx.x * 4;
  int offs[8];
  {
    int o = 0;
#pragma unroll
    for (int e = 0; e < 8; ++e) { offs[e] = o; o += cnt[e]; }
  }
  const int t0 = tokslot[2 * tok], t1 = tokslot[2 * tok + 1];
  const float g0 = tw[2 * tok], g1 = tw[2 * tok + 1];
  const int r0 = offs[t0 >> 16] + (t0 & 0xffff);
  const int r1 = offs[t1 >> 16] + (t1 & 0xffff);
  const int rs = 2048 + tok;
  float4 acc; acc.x = 0.f; acc.y = 0.f; acc.z = 0.f; acc.w = 0.f;
#pragma unroll
  for (int kc = 0; kc < 4; ++kc) {
    const float* base = pout + (size_t)kc * 3072 * CDIM;
    float4 a = *reinterpret_cast<const float4*>(base + (size_t)rs * CDIM + c);
    float4 b = *reinterpret_cast<const float4*>(base + (size_t)r0 * CDIM + c);
    float4 d = *reinterpret_cast<const float4*>(base + (size_t)r1 * CDIM + c);
    acc.x += a.x + g0 * b.x + g1 * d.x;
    acc.y += a.y + g0 * b.y + g1 * d.y;
    acc.z += a.z + g0 * b.z + g1 * d.z;
    acc.w += a.w + g0 * b.w + g1 * d.w;
  }
  *reinterpret_cast<float4*>(out + (size_t)tok * CDIM + c) = acc;
}

extern "C" void kernel_launch(void* const* d_in, const int* in_sizes, int n_in,
                              void* d_out, int out_size, void* d_ws, size_t ws_size,
                              hipStream_t stream) {
  const float* x = (const float*)d_in[0];
  const float* Wr1 = (const float*)d_in[1];
  const float* br1 = (const float*)d_in[2];
  const float* Wr2 = (const float*)d_in[3];
  const float* br2 = (const float*)d_in[4];
  const float* Ws1 = (const float*)d_in[5];
  const float* bs1 = (const float*)d_in[6];
  const float* Ws2 = (const float*)d_in[7];
  const float* bs2 = (const float*)d_in[8];
  const float* We1 = (const float*)d_in[9];
  const float* be1 = (const float*)d_in[10];
  const float* We2 = (const float*)d_in[11];
  const float* be2 = (const float*)d_in[12];
  float* out = (float*)d_out;

  char* ws = (char*)d_ws;
  unsigned short* xb = (unsigned short*)(ws + 0);            // 2 MB
  int* ti = (int*)(ws + 2097152);
  float* tw = (float*)(ws + 2105344);
  int* cnt = (int*)(ws + 2113536);
  int* list = (int*)(ws + 2114048);                          // 32 KB
  unsigned short* H = (unsigned short*)(ws + 2179584);       // 24 MB -> 27345408
  int* tokslot = (int*)(ws + 27345920);                      // 8 KB -> 27354112
  float* pout = (float*)(ws + 27354112ull);                  // 48 MB -> 77687808

  init_cast_kernel<<<1024, 256, 0, stream>>>(x, xb);
  router_kernel<<<NTOK / RT, 256, 0, stream>>>(x, Wr1, br1, Wr2, br2, ti, tw);
  build_lists_kernel<<<8, 1024, 0, stream>>>(ti, tw, cnt, list, tokslot);
  gemm_w<0><<<dim3(32, 20), 512, 0, stream>>>(xb, We1, Ws1, be1, bs1, cnt, list,
                                              H, nullptr);
  gemm_w<1><<<dim3(32, 20), 512, 0, stream>>>(H, We2, Ws2, be2, bs2, cnt, list,
                                              nullptr, pout);
  reduce_kernel<<<1024, 256, 0, stream>>>(pout, tokslot, tw, cnt, out);
}

// Round 14
// 219.055 us; speedup vs baseline: 1.7250x; 1.0821x over previous
//
#include <hip/hip_runtime.h>

#define NTOK 1024
#define CDIM 1024
#define CRDIM 256
#define ENUM 8
#define IDIM 4096
#define WSTRIDE 4194304ull  // C*I elements per expert weight matrix

typedef __bf16 bf16x8 __attribute__((ext_vector_type(8)));
typedef __bf16 bf16x4 __attribute__((ext_vector_type(4)));
typedef float f32x4 __attribute__((ext_vector_type(4)));

typedef const unsigned int __attribute__((address_space(1))) gu32;
typedef unsigned int __attribute__((address_space(3))) lu32;

__device__ __forceinline__ void glds16(const unsigned short* g, unsigned short* l) {
  __builtin_amdgcn_global_load_lds((gu32*)g, (lu32*)l, 16, 0, 0);
}

__device__ __forceinline__ unsigned short f2bf(float f) {
  union { float f; unsigned int u; } v; v.f = f;
  unsigned int r = v.u + 0x7FFFu + ((v.u >> 16) & 1u);  // RNE
  return (unsigned short)(r >> 16);
}

// ---------------- cast x to bf16 ----------------
__global__ __launch_bounds__(256) void init_cast_kernel(
    const float* __restrict__ x, unsigned short* __restrict__ xb) {
  int t = blockIdx.x * 256 + threadIdx.x;
  float4 v = reinterpret_cast<const float4*>(x)[t];
  ushort4 o;
  o.x = f2bf(v.x); o.y = f2bf(v.y); o.z = f2bf(v.z); o.w = f2bf(v.w);
  reinterpret_cast<ushort4*>(xb)[t] = o;
}

// ---------------- router: gates + top-2 (LDS x-stage) ----------------
#define RT 8
__global__ __launch_bounds__(256) void router_kernel(
    const float* __restrict__ x, const float* __restrict__ Wr1,
    const float* __restrict__ br1, const float* __restrict__ Wr2,
    const float* __restrict__ br2, int* __restrict__ ti,
    float* __restrict__ tw) {
  __shared__ float xs[RT][CDIM];
  __shared__ float hs[RT][CRDIM];
  __shared__ float lg[RT][ENUM];
  const int tid = threadIdx.x;
  const int tok0 = blockIdx.x * RT;
  for (int r = 0; r < RT; ++r) {
    float4 v = reinterpret_cast<const float4*>(x + (size_t)(tok0 + r) * CDIM)[tid];
    *reinterpret_cast<float4*>(&xs[r][tid * 4]) = v;
  }
  __syncthreads();
  float acc[RT];
#pragma unroll
  for (int r = 0; r < RT; ++r) acc[r] = 0.f;
  const int j = tid;
  for (int i = 0; i < CDIM; ++i) {
    float w = Wr1[(size_t)i * CRDIM + j];
#pragma unroll
    for (int r = 0; r < RT; ++r) acc[r] += xs[r][i] * w;
  }
  float b = br1[j];
#pragma unroll
  for (int r = 0; r < RT; ++r) hs[r][j] = fmaxf(acc[r] + b, 0.f);
  __syncthreads();
  if (tid < RT * ENUM) {
    int r = tid >> 3, e = tid & 7;
    float a = 0.f;
    for (int i = 0; i < CRDIM; ++i) a += hs[r][i] * Wr2[(size_t)i * ENUM + e];
    lg[r][e] = a + br2[e];
  }
  __syncthreads();
  if (tid < RT) {
    int r = tid;
    float m = lg[r][0];
#pragma unroll
    for (int e = 1; e < 8; ++e) m = fmaxf(m, lg[r][e]);
    float s = 0.f, g[8];
#pragma unroll
    for (int e = 0; e < 8; ++e) { g[e] = expf(lg[r][e] - m); s += g[e]; }
    float inv = 1.f / s;
    int i0 = 0; float g0 = -1.f;
#pragma unroll
    for (int e = 0; e < 8; ++e) { float ge = g[e] * inv; if (ge > g0) { g0 = ge; i0 = e; } }
    int i1 = 0; float g1 = -2.f;
#pragma unroll
    for (int e = 0; e < 8; ++e) { float ge = g[e] * inv; if (e != i0 && ge > g1) { g1 = ge; i1 = e; } }
    float w0 = 1.f / (1.f + expf((g1 - g0) * 0.5f));
    int n = tok0 + r;
    ti[2 * n] = i0; ti[2 * n + 1] = i1;
    tw[2 * n] = w0; tw[2 * n + 1] = 1.f - w0;
  }
}

// ---------------- per-expert token lists (stable order) + tokslot map ---------
__global__ __launch_bounds__(1024) void build_lists_kernel(
    const int* __restrict__ ti, const float* __restrict__ tw,
    int* __restrict__ cnt, int* __restrict__ list, int* __restrict__ tokslot) {
  __shared__ int s[NTOK];
  const int e = blockIdx.x, n = threadIdx.x;
  int a = ti[2 * n], b = ti[2 * n + 1];
  int flag = (a == e || b == e) ? 1 : 0;
  s[n] = flag;
  __syncthreads();
  for (int off = 1; off < NTOK; off <<= 1) {
    int v = (n >= off) ? s[n - off] : 0;
    __syncthreads();
    s[n] += v;
    __syncthreads();
  }
  if (flag) {
    int pos = s[n] - 1;
    list[e * NTOK + pos] = n;
    int slot = (a == e) ? 0 : 1;
    tokslot[2 * n + slot] = (e << 16) | pos;
  }
  if (n == NTOK - 1) cnt[e] = s[n];
}

// uniform helper: y -> (expert, row0, hbase) over 256-row tiles
__device__ __forceinline__ bool tile_lookup(const int* __restrict__ cnt, int y,
                                            int& e_out, int& row0_out,
                                            int& hbase_out) {
  int c[8];
#pragma unroll
  for (int i = 0; i < 8; ++i) c[i] = cnt[i];
  int k = 0, found = -1, r0 = 0, pre = 0, hb = 0;
#pragma unroll
  for (int ee = 0; ee < 9; ++ee) {
    int me = (ee < 8) ? c[ee] : NTOK;
    int nt_e = (me + 255) >> 8;
    if (found < 0 && y < k + nt_e) {
      found = ee; r0 = (y - k) << 8; hb = (ee < 8) ? pre : 2048;
    }
    k += nt_e;
    if (ee < 8) pre += me;
  }
  if (found < 0) return false;
  e_out = found; row0_out = r0; hbase_out = hb;
  return true;
}

// ---- 512-thread 256x128 GEMM, direct f32 weights, counted-vmcnt pipeline ----
// (round-9 structure: A 3-deep glds16; B 2-LDS-buf + 2-reg-set bridge; vmcnt(4))
// MODE 0: H[hrow] = silu(Xg @ W1 + b1)            (bf16 store), K-chunk 1024
// MODE 1: pout[kc][hrow] = H @ W2 (+b2 @ kc==0)   (f32 plain store, split-K=2,
//                                                  K-chunk 2048)
template <int MODE>
__global__ __launch_bounds__(512, 4) void gemm_w(
    const unsigned short* __restrict__ Abase,
    const float* __restrict__ Wr, const float* __restrict__ Wsh,
    const float* __restrict__ br, const float* __restrict__ bsh,
    const int* __restrict__ cnt, const int* __restrict__ list,
    unsigned short* __restrict__ Hout, float* __restrict__ pout) {
  __shared__ __align__(16) unsigned short smA[3 * 8192];  // 3 x [256m][32k] bf16
  __shared__ __align__(16) unsigned short smB[2 * 5120];  // 2 x [128n][40] bf16
  int e, row0, hbase;
  if (!tile_lookup(cnt, blockIdx.y, e, row0, hbase)) return;
  const int nt = (MODE == 0) ? blockIdx.x : (blockIdx.x & 7);
  const int kc = (MODE == 0) ? 0 : (blockIdx.x >> 3);

  constexpr int KD = (MODE == 0) ? CDIM : IDIM;   // A row length
  constexpr int ND = (MODE == 0) ? IDIM : CDIM;   // B row length (f32 [K][N])
  constexpr int KCH = (MODE == 0) ? 1024 : 2048;  // K-chunk per block
  constexpr int NT = KCH / 32;                    // 32 or 64
  const int me = (e < 8) ? cnt[e] : NTOK;
  const int valid = min(256, me - row0);
  const int n0 = nt * 128;
  const float* Bsrc = (e < 8) ? (Wr + (size_t)e * WSTRIDE) : Wsh;
  const float* bias = (e < 8) ? (br + (size_t)e * ND) : bsh;
  const int tid = threadIdx.x;
  const int lane = tid & 63, w = tid >> 6;
  const int kbeg = kc * KCH;

  // ---- A staging (glds16): wave w rows [32w,32w+16) and [32w+16,32w+32) ----
  const int rl = lane >> 2, cs = lane & 3;
  const int r0w = 32 * w + rl;
  const int q0 = cs ^ ((r0w >> 1) & 3);
  const int q1 = cs ^ (((r0w + 16) >> 1) & 3);
  int src_r0, src_r1;
  if (MODE == 0) {
    if (e < 8) {
      src_r0 = list[e * NTOK + row0 + min(r0w, valid - 1)];
      src_r1 = list[e * NTOK + row0 + min(r0w + 16, valid - 1)];
    } else {
      src_r0 = row0 + min(r0w, valid - 1);
      src_r1 = row0 + min(r0w + 16, valid - 1);
    }
  } else {
    src_r0 = hbase + row0 + min(r0w, valid - 1);
    src_r1 = hbase + row0 + min(r0w + 16, valid - 1);
  }
  const unsigned short* srcA0 = Abase + (size_t)src_r0 * KD + kbeg + q0 * 8;
  const unsigned short* srcA1 = Abase + (size_t)src_r1 * KD + kbeg + q1 * 8;
  const int aB0 = (32 * w) * 32;
  const int aB1 = (32 * w + 16) * 32;

  // ---- B staging: thread -> 4 cols {c4..c4+3} at k-pair kp ----
  const int c4 = (tid & 31) * 4;
  const int kp = tid >> 5;  // 0..15
  const float* srcB = Bsrc + (size_t)(kbeg + 2 * kp) * ND + n0 + c4;

  // ---- fragment offsets: wave grid 4M x 2N; per-wave 64m x 64n ----
  const int wr = (w >> 1) * 64, wc = (w & 1) * 64;
  const int lr = lane & 15, q = lane >> 4;
  int offA[4], offB0[4];
#pragma unroll
  for (int m = 0; m < 4; ++m) {
    int R = wr + m * 16 + lr;
    offA[m] = R * 32 + (q ^ ((R >> 1) & 3)) * 8;
  }
#pragma unroll
  for (int n = 0; n < 4; ++n) {
    int R = wc + n * 16 + lr;
    int u = (R >> 3) & 7;
    offB0[n] = R * 40 + ((2 * q) ^ u) * 4;  // hi half at ^4
  }

  f32x4 acc[4][4];
#pragma unroll
  for (int m = 0; m < 4; ++m)
#pragma unroll
    for (int n = 0; n < 4; ++n) acc[m][n] = (f32x4)0.f;

  unsigned short *ca = smA, *na = smA + 8192, *wa = smA + 16384;
  unsigned short *bc = smB, *bn = smB + 5120;
  f32x4 rbA[2], rbB[2];

#define ASTG(T, BA)                                       \
  {                                                       \
    glds16(srcA0 + (size_t)(T) * 32, (BA) + aB0);         \
    glds16(srcA1 + (size_t)(T) * 32, (BA) + aB1);         \
  }
#define BLOAD(T, R)                                       \
  {                                                       \
    const float* bp = srcB + (size_t)(T) * 32 * ND;       \
    R[0] = *reinterpret_cast<const f32x4*>(bp);           \
    R[1] = *reinterpret_cast<const f32x4*>(bp + ND);      \
  }
#define BWRITE(R, BB)                                                          \
  {                                                                            \
    _Pragma("unroll") for (int j = 0; j < 4; ++j) {                            \
      int col = c4 + j;                                                        \
      int kp2 = kp ^ (2 * ((col >> 3) & 7));                                   \
      unsigned int pk =                                                        \
          (unsigned int)__builtin_bit_cast(unsigned short, (__bf16)R[0][j]) |  \
          ((unsigned int)__builtin_bit_cast(unsigned short, (__bf16)R[1][j])   \
           << 16);                                                             \
      *reinterpret_cast<unsigned int*>((BB) + col * 40 + kp2 * 2) = pk;        \
    }                                                                          \
  }
#define MFMAS()                                                                \
  {                                                                            \
    bf16x8 av[4];                                                              \
    _Pragma("unroll") for (int m = 0; m < 4; ++m)                              \
        av[m] = *reinterpret_cast<const bf16x8*>(ca + offA[m]);                \
    _Pragma("unroll") for (int n = 0; n < 4; ++n) {                            \
      bf16x4 lo = *reinterpret_cast<const bf16x4*>(bc + offB0[n]);             \
      bf16x4 hi = *reinterpret_cast<const bf16x4*>(bc + (offB0[n] ^ 4));       \
      bf16x8 bv = __builtin_shufflevector(lo, hi, 0, 1, 2, 3, 4, 5, 6, 7);     \
      _Pragma("unroll") for (int m = 0; m < 4; ++m)                            \
          acc[m][n] = __builtin_amdgcn_mfma_f32_16x16x32_bf16(av[m], bv,       \
                                                              acc[m][n], 0,   \
                                                              0, 0);           \
    }                                                                          \
  }

  // prologue: tiles 0,1 in flight; publish tile 0
  ASTG(0, ca); BLOAD(0, rbA);
  __builtin_amdgcn_sched_barrier(0);
  ASTG(1, na); BLOAD(1, rbB);
  asm volatile("s_waitcnt vmcnt(4)" ::: "memory");  // tile0 A in LDS, B in regs
  __builtin_amdgcn_sched_barrier(0);
  BWRITE(rbA, bc);
  asm volatile("s_waitcnt lgkmcnt(0)" ::: "memory");
  __builtin_amdgcn_s_barrier();
  __builtin_amdgcn_sched_barrier(0);

#define GBODY(T, RL, RW)                                                     \
  {                                                                          \
    if ((T) + 2 < NT) { ASTG((T) + 2, wa); BLOAD((T) + 2, RL); }             \
    MFMAS();                                                                 \
    if ((T) + 1 < NT) {                                                      \
      if ((T) + 2 < NT) {                                                    \
        asm volatile("s_waitcnt vmcnt(4)" ::: "memory");                     \
      } else {                                                               \
        asm volatile("s_waitcnt vmcnt(0)" ::: "memory");                     \
      }                                                                      \
      __builtin_amdgcn_sched_barrier(0);                                     \
      BWRITE(RW, bn);                                                        \
      asm volatile("s_waitcnt lgkmcnt(0)" ::: "memory");                     \
      __builtin_amdgcn_s_barrier();                                          \
      __builtin_amdgcn_sched_barrier(0);                                     \
    }                                                                        \
    { unsigned short* tp = ca; ca = na; na = wa; wa = tp; }                  \
    { unsigned short* tp = bc; bc = bn; bn = tp; }                           \
  }

  for (int t = 0; t < NT; t += 2) {
    GBODY(t, rbA, rbB)
    GBODY(t + 1, rbB, rbA)
  }
#undef GBODY
#undef MFMAS
#undef BWRITE
#undef BLOAD
#undef ASTG

  const int rbase = wr + (q << 2);
#pragma unroll
  for (int n = 0; n < 4; ++n) {
    const int col = n0 + wc + n * 16 + lr;
    const float bval = (MODE == 0 || kc == 0) ? bias[col] : 0.f;
#pragma unroll
    for (int m = 0; m < 4; ++m) {
#pragma unroll
      for (int r = 0; r < 4; ++r) {
        const int i = rbase + m * 16 + r;
        if (i < valid) {
          float v = acc[m][n][r] + bval;
          if (MODE == 0) {
            float sv = v / (1.f + __expf(-v));
            Hout[(size_t)(hbase + row0 + i) * IDIM + col] = f2bf(sv);
          } else {
            pout[((size_t)kc * 3072 + hbase + row0 + i) * CDIM + col] = v;
          }
        }
      }
    }
  }
}

// out[tok][c] = sum_kc( pout[kc][shared] + g0*pout[kc][h0] + g1*pout[kc][h1] )
__global__ __launch_bounds__(256) void reduce_kernel(
    const float* __restrict__ pout, const int* __restrict__ tokslot,
    const float* __restrict__ tw, const int* __restrict__ cnt,
    float* __restrict__ out) {
  const int tok = blockIdx.x;
  const int c = threadIdx.x * 4;
  int offs[8];
  {
    int o = 0;
#pragma unroll
    for (int e = 0; e < 8; ++e) { offs[e] = o; o += cnt[e]; }
  }
  const int t0 = tokslot[2 * tok], t1 = tokslot[2 * tok + 1];
  const float g0 = tw[2 * tok], g1 = tw[2 * tok + 1];
  const int r0 = offs[t0 >> 16] + (t0 & 0xffff);
  const int r1 = offs[t1 >> 16] + (t1 & 0xffff);
  const int rs = 2048 + tok;
  float4 acc; acc.x = 0.f; acc.y = 0.f; acc.z = 0.f; acc.w = 0.f;
#pragma unroll
  for (int kc = 0; kc < 2; ++kc) {
    const float* base = pout + (size_t)kc * 3072 * CDIM;
    float4 a = *reinterpret_cast<const float4*>(base + (size_t)rs * CDIM + c);
    float4 b = *reinterpret_cast<const float4*>(base + (size_t)r0 * CDIM + c);
    float4 d = *reinterpret_cast<const float4*>(base + (size_t)r1 * CDIM + c);
    acc.x += a.x + g0 * b.x + g1 * d.x;
    acc.y += a.y + g0 * b.y + g1 * d.y;
    acc.z += a.z + g0 * b.z + g1 * d.z;
    acc.w += a.w + g0 * b.w + g1 * d.w;
  }
  *reinterpret_cast<float4*>(out + (size_t)tok * CDIM + c) = acc;
}

extern "C" void kernel_launch(void* const* d_in, const int* in_sizes, int n_in,
                              void* d_out, int out_size, void* d_ws, size_t ws_size,
                              hipStream_t stream) {
  const float* x = (const float*)d_in[0];
  const float* Wr1 = (const float*)d_in[1];
  const float* br1 = (const float*)d_in[2];
  const float* Wr2 = (const float*)d_in[3];
  const float* br2 = (const float*)d_in[4];
  const float* Ws1 = (const float*)d_in[5];
  const float* bs1 = (const float*)d_in[6];
  const float* Ws2 = (const float*)d_in[7];
  const float* bs2 = (const float*)d_in[8];
  const float* We1 = (const float*)d_in[9];
  const float* be1 = (const float*)d_in[10];
  const float* We2 = (const float*)d_in[11];
  const float* be2 = (const float*)d_in[12];
  float* out = (float*)d_out;

  char* ws = (char*)d_ws;
  unsigned short* xb = (unsigned short*)(ws + 0);            // 2 MB
  int* ti = (int*)(ws + 2097152);
  float* tw = (float*)(ws + 2105344);
  int* cnt = (int*)(ws + 2113536);
  int* list = (int*)(ws + 2114048);                          // 32 KB
  unsigned short* H = (unsigned short*)(ws + 2179584);       // 24 MB -> 27345408
  int* tokslot = (int*)(ws + 27345920);                      // 8 KB -> 27354112
  float* pout = (float*)(ws + 27354112ull);                  // 24 MB -> 52520960

  init_cast_kernel<<<1024, 256, 0, stream>>>(x, xb);
  router_kernel<<<NTOK / RT, 256, 0, stream>>>(x, Wr1, br1, Wr2, br2, ti, tw);
  build_lists_kernel<<<8, 1024, 0, stream>>>(ti, tw, cnt, list, tokslot);
  gemm_w<0><<<dim3(32, 20), 512, 0, stream>>>(xb, We1, Ws1, be1, bs1, cnt, list,
                                              H, nullptr);
  gemm_w<1><<<dim3(16, 20), 512, 0, stream>>>(H, We2, Ws2, be2, bs2, cnt, list,
                                              nullptr, pout);
  reduce_kernel<<<1024, 256, 0, stream>>>(pout, tokslot, tw, cnt, out);
}